// Round 7
// baseline (76.580 us; speedup 1.0000x reference)
//
#include <hip/hip_runtime.h>
#include <math.h>

// query [4,32,64,64] f32, key [4,32,64,192] f32
#define B 4
#define C 32
#define H 64
#define WQ 64
#define WK 192
#define NP 129                    // P = 192 - 64 + 1
#define ROWS (C * H)              // 2048 rows per batch
#define ELEMS (ROWS * WQ)         // 131072 elements per (b,p)
#define GB 256                    // blocks per batch
#define WPB 4                     // waves per block
#define RPW (ROWS / (GB * WPB))   // rows per wave = 2
#define TOTAL (B * GB)            // 1024 blocks

// Workspace layout (zeroed by the memset in kernel_launch):
//   ws[0 .. B*NP-1]  : float sums, accumulated by atomicAdd
//   ws[B*NP]         : uint ticket counter
__global__ __launch_bounds__(256, 4) void patch_l1_fused(const float* __restrict__ query,
                                                          const float* __restrict__ key,
                                                          float* __restrict__ sums,
                                                          unsigned int* __restrict__ counter,
                                                          float* __restrict__ out) {
    __shared__ __align__(16) float kbuf[WPB][RPW * WK];   // 1.5 KB per wave
    __shared__ float red[WPB][NP];
    __shared__ int   is_last;

    const int bid  = blockIdx.x;
    const int b    = bid >> 8;           // / GB
    const int g    = bid & (GB - 1);
    const int t    = threadIdx.x;
    const int wv   = t >> 6;
    const int lane = t & 63;
    const int slot = __builtin_amdgcn_readfirstlane(g * WPB + (t >> 6));
    const int r0   = slot * RPW;         // this wave's two rows

    const float* __restrict__ qb = query + (size_t)b * ELEMS;
    const float* __restrict__ kb = key   + (size_t)b * ROWS * WK + (size_t)r0 * WK;

    // ---- Phase A (identical structure to round-4 best) ----
    if (lane < 48) {
        const float4 k0v = *reinterpret_cast<const float4*>(kb + lane * 4);
        const float4 k1v = *reinterpret_cast<const float4*>(kb + WK + lane * 4);
        *reinterpret_cast<float4*>(&kbuf[wv][lane * 4])      = k0v;
        *reinterpret_cast<float4*>(&kbuf[wv][WK + lane * 4]) = k1v;
    }
    const float q0l = qb[(size_t)r0 * WQ + lane];
    const float q1l = qb[(size_t)(r0 + 1) * WQ + lane];

    const float* __restrict__ q0 = qb + (size_t)r0 * WQ;         // uniform -> s_load
    const float* __restrict__ q1 = qb + (size_t)(r0 + 1) * WQ;   // uniform -> s_load
    const float* __restrict__ k0 = &kbuf[wv][0];
    const float* __restrict__ k1 = &kbuf[wv][WK];

    float a0 = 0.f, b0 = 0.f, a1 = 0.f, b1 = 0.f, acc2 = 0.f;

    #pragma unroll
    for (int si = 0; si < 33; ++si) {
        const int s = si * 2;
        const float2 ka = *reinterpret_cast<const float2*>(&k0[2 * lane + s]);
        const float2 kc = *reinterpret_cast<const float2*>(&k1[2 * lane + s]);
        if (si < 32) {
            a0 += fabsf(ka.x - q0[s]) + fabsf(ka.y - q0[s + 1]);
            a1 += fabsf(kc.x - q1[s]) + fabsf(kc.y - q1[s + 1]);
            b0 += fabsf(ka.y - q0[s]);
            b1 += fabsf(kc.y - q1[s]);
            if (si > 0) {
                b0 += fabsf(ka.x - q0[s - 1]);
                b1 += fabsf(kc.x - q1[s - 1]);
            }
        } else {   // s = 64: only the p=2l+1 (w=63) term
            b0 += fabsf(ka.x - q0[63]);
            b1 += fabsf(kc.x - q1[63]);
        }
    }
    acc2 += fabsf(k0[128 + lane] - q0l);
    acc2 += fabsf(k1[128 + lane] - q1l);
    #pragma unroll
    for (int m = 32; m; m >>= 1) acc2 += __shfl_xor(acc2, m, 64);

    red[wv][2 * lane]     = a0 + a1;
    red[wv][2 * lane + 1] = b0 + b1;
    if (lane == 0) red[wv][128] = acc2;
    __syncthreads();

    // ---- cross-block accumulate: one atomicAdd per (b,p) per block ----
    if (t < NP) {
        const float v = red[0][t] + red[1][t] + red[2][t] + red[3][t];
        atomicAdd(&sums[b * NP + t], v);
    }

    // ---- ticket: last block finalizes ----
    __threadfence();
    if (t == 0) {
        const unsigned int old = atomicAdd(counter, 1u);
        is_last = (old == TOTAL - 1u) ? 1 : 0;
    }
    __syncthreads();
    if (!is_last) return;

    __threadfence();
    // wave wv owns batch wv; volatile reads bypass L1 (coherent with L2 atomics)
    const volatile float* __restrict__ vs = (const volatile float*)(sums + wv * NP);
    const float inv = 1.0f / (float)ELEMS;

    const float y0 = vs[lane] * inv;          // p = lane
    const float y1 = vs[64 + lane] * inv;     // p = 64 + lane
    float best  = y0;
    int   besti = lane;
    if (y1 < best) { best = y1; besti = 64 + lane; }
    if (lane == 0) {
        const float y2 = vs[128] * inv;       // p = 128
        if (y2 < best) { best = y2; besti = 128; }
    }

    #pragma unroll
    for (int m = 32; m; m >>= 1) {
        const float yo = __shfl_xor(best, m, 64);
        const int   io = __shfl_xor(besti, m, 64);
        if (yo < best || (yo == best && io < besti)) { best = yo; besti = io; }
    }

    if (lane == 0) {
        out[wv]     = (float)besti;   // hard_indices[b]
        out[5 + wv] = best;           // relevance min
        if (wv == 0) out[4] = (float)NP;
    }
}

extern "C" void kernel_launch(void* const* d_in, const int* in_sizes, int n_in,
                              void* d_out, int out_size, void* d_ws, size_t ws_size,
                              hipStream_t stream) {
    const float* query = (const float*)d_in[0];
    const float* key   = (const float*)d_in[1];
    float* out  = (float*)d_out;
    float* sums = (float*)d_ws;                               // 516 floats
    unsigned int* counter = (unsigned int*)(sums + B * NP);   // 1 uint

    hipMemsetAsync(d_ws, 0, (B * NP + 1) * sizeof(float), stream);
    patch_l1_fused<<<TOTAL, 256, 0, stream>>>(query, key, sums, counter, out);
}

// Round 8
// 19.366 us; speedup vs baseline: 3.9544x; 3.9544x over previous
//
#include <hip/hip_runtime.h>
#include <math.h>

// query [4,32,64,64] f32, key [4,32,64,192] f32
#define B 4
#define C 32
#define H 64
#define WQ 64
#define WK 192
#define NP 129                    // P = 192 - 64 + 1
#define ROWS (C * H)              // 2048 rows per batch
#define ELEMS (ROWS * WQ)         // 131072 elements per (b,p)
#define GB 256                    // blocks per batch
#define WPB 4                     // waves per block
#define RPW 2                     // rows per wave
#define PSTRIDE 132               // padded partial-row stride (floats)
#define KPAD 200                  // padded LDS k-row stride

// Kernel A: lane l owns shifts p=2l, p=2l+1. Rows processed SEQUENTIALLY so the
// row's 64 q-values fit in SGPRs (s_load_dwordx16 up-front, no SMEM inside the
// loop -> no lgkmcnt(0) drains of the DS pipe). Inner loop is pure
// {ds_read2_b64 + VALU} with 4 independent accumulator chains.
__global__ __launch_bounds__(256, 4) void patch_l1_partial(const float* __restrict__ query,
                                                           const float* __restrict__ key,
                                                           float* __restrict__ part) {
    __shared__ __align__(16) float kbuf[WPB][RPW][KPAD];  // 2 k-rows per wave
    __shared__ float red[WPB][130];                       // padded for float2 writes

    const int bid  = blockIdx.x;
    const int b    = bid >> 8;           // / GB
    const int g    = bid & (GB - 1);
    const int t    = threadIdx.x;
    const int wv   = t >> 6;
    const int lane = t & 63;
    const int slot = __builtin_amdgcn_readfirstlane(g * WPB + (t >> 6));
    const int r0   = slot * RPW;         // this wave's two rows

    const float* __restrict__ qb = query + (size_t)b * ELEMS;
    const float* __restrict__ kb = key   + (size_t)b * ROWS * WK + (size_t)r0 * WK;

    // stage both k-rows into wave-private LDS (lane<48: one float4 per row)
    if (lane < 48) {
        const float4 v0 = *reinterpret_cast<const float4*>(kb + lane * 4);
        const float4 v1 = *reinterpret_cast<const float4*>(kb + WK + lane * 4);
        *reinterpret_cast<float4*>(&kbuf[wv][0][lane * 4]) = v0;
        *reinterpret_cast<float4*>(&kbuf[wv][1][lane * 4]) = v1;
    }
    // per-lane q values for the p=128 terms
    const float q0l = qb[(size_t)r0 * WQ + lane];
    const float q1l = qb[(size_t)(r0 + 1) * WQ + lane];

    float acc_a = 0.f, acc_b = 0.f, acc2 = 0.f;

    #pragma unroll
    for (int rr = 0; rr < RPW; ++rr) {
        // hoist the row's q into SGPRs: uniform pointer + compile-time offsets
        const float* __restrict__ qr = qb + (size_t)(r0 + rr) * WQ;
        float qs[64];
        #pragma unroll
        for (int s4 = 0; s4 < 16; ++s4) {
            const float4 qv = *reinterpret_cast<const float4*>(qr + s4 * 4);
            qs[s4 * 4 + 0] = qv.x; qs[s4 * 4 + 1] = qv.y;
            qs[s4 * 4 + 2] = qv.z; qs[s4 * 4 + 3] = qv.w;
        }

        const float* __restrict__ k0 = &kbuf[wv][rr][0];
        float aa0 = 0.f, aa1 = 0.f, bb0 = 0.f, bb1 = 0.f;

        #pragma unroll
        for (int si = 0; si < 16; ++si) {
            const int s = si * 4;
            // k[2l+s .. 2l+s+3] as two 8B-aligned float2 (fusible to ds_read2_b64)
            const float2 ka = *reinterpret_cast<const float2*>(&k0[2 * lane + s]);
            const float2 kc = *reinterpret_cast<const float2*>(&k0[2 * lane + s + 2]);
            aa0 += fabsf(ka.x - qs[s]);                    // p=2l,   w=s
            if (si > 0) bb0 += fabsf(ka.x - qs[s - 1]);    // p=2l+1, w=s-1
            aa1 += fabsf(ka.y - qs[s + 1]);                // p=2l,   w=s+1
            bb1 += fabsf(ka.y - qs[s]);                    // p=2l+1, w=s
            aa0 += fabsf(kc.x - qs[s + 2]);                // p=2l,   w=s+2
            bb0 += fabsf(kc.x - qs[s + 1]);                // p=2l+1, w=s+1
            aa1 += fabsf(kc.y - qs[s + 3]);                // p=2l,   w=s+3
            bb1 += fabsf(kc.y - qs[s + 2]);                // p=2l+1, w=s+2
        }
        bb0 += fabsf(k0[2 * lane + 64] - qs[63]);          // tail: p=2l+1, w=63

        acc_a += aa0 + aa1;
        acc_b += bb0 + bb1;
        acc2  += fabsf(k0[128 + lane] - (rr ? q1l : q0l)); // p=128, w=lane
    }

    // wave-reduce the p=128 accumulator across 64 lanes
    #pragma unroll
    for (int m = 32; m; m >>= 1) acc2 += __shfl_xor(acc2, m, 64);

    *reinterpret_cast<float2*>(&red[wv][2 * lane]) = make_float2(acc_a, acc_b);
    if (lane == 0) red[wv][128] = acc2;
    __syncthreads();

    if (t < NP)
        part[(size_t)bid * PSTRIDE + t] = red[0][t] + red[1][t] + red[2][t] + red[3][t];
}

// Kernel B: one 1024-thread block per batch; wave wv accumulates g = wv, wv+16, ...
// (coalesced 256 B reads), 16-way LDS combine, then first-index min/argmin tree.
__global__ __launch_bounds__(1024) void patch_l1_final(const float* __restrict__ part,
                                                       float* __restrict__ out) {
    const int b    = blockIdx.x;
    const int t    = threadIdx.x;
    const int wv   = t >> 6;       // 0..15
    const int lane = t & 63;

    float acc0 = 0.f, acc1 = 0.f, acc2 = 0.f;
    #pragma unroll 4
    for (int g = wv; g < GB; g += 16) {
        const float* __restrict__ src = part + ((size_t)b * GB + g) * PSTRIDE;
        acc0 += src[lane];
        acc1 += src[64 + lane];
        if (lane == 0) acc2 += src[128];
    }

    __shared__ float red[16][NP];
    red[wv][lane]      = acc0;
    red[wv][64 + lane] = acc1;
    if (lane == 0) red[wv][128] = acc2;
    __syncthreads();

    float y = INFINITY;
    int idx = NP;
    if (t < NP) {
        float s = 0.f;
        #pragma unroll
        for (int w = 0; w < 16; ++w) s += red[w][t];
        y = s * (1.0f / (float)ELEMS);
        idx = t;
    }

    __shared__ float sy[256];
    __shared__ int   si[256];
    if (t < 256) { sy[t] = y; si[t] = idx; }
    __syncthreads();
    #pragma unroll
    for (int s = 128; s > 0; s >>= 1) {
        if (t < s) {
            const float yo = sy[t + s];
            const int   io = si[t + s];
            if (yo < sy[t] || (yo == sy[t] && io < si[t])) {
                sy[t] = yo;
                si[t] = io;
            }
        }
        __syncthreads();
    }

    if (t == 0) {
        out[b]     = (float)si[0];
        out[5 + b] = sy[0];
        if (b == 0) out[4] = (float)NP;
    }
}

extern "C" void kernel_launch(void* const* d_in, const int* in_sizes, int n_in,
                              void* d_out, int out_size, void* d_ws, size_t ws_size,
                              hipStream_t stream) {
    const float* query = (const float*)d_in[0];
    const float* key   = (const float*)d_in[1];
    float* out  = (float*)d_out;
    float* part = (float*)d_ws;   // B*GB*PSTRIDE floats = 540 KB, block-owned

    patch_l1_partial<<<B * GB, 256, 0, stream>>>(query, key, part);
    patch_l1_final<<<B, 1024, 0, stream>>>(part, out);
}